// Round 8
// baseline (247.326 us; speedup 1.0000x reference)
//
#include <hip/hip_runtime.h>
#include <cstdint>

#define S_LEN 2048
#define D_MODEL 1024
#define NH 16
#define HDIM 64
#define BATCH 4

typedef __attribute__((ext_vector_type(8))) __bf16 bfrag;   // 8 bf16 = 4 VGPR
typedef __attribute__((ext_vector_type(4))) float ffrag;    // 4 f32 acc

__device__ __forceinline__ unsigned short f2bf(float f) {
    union { float f; uint32_t u; } v; v.f = f;
    uint32_t u = v.u;
    u += 0x7fff + ((u >> 16) & 1);   // round-to-nearest-even
    return (unsigned short)(u >> 16);
}

__device__ __forceinline__ bfrag ld_frag(const unsigned short* p) {
    union { uint4 u; bfrag b; } x;
    x.u = *(const uint4*)p;
    return x.b;
}

__device__ __forceinline__ float fast_exp2(float x) {
#if __has_builtin(__builtin_amdgcn_exp2f)
    return __builtin_amdgcn_exp2f(x);
#else
    return __expf(x * 0.6931471805599453f);
#endif
}

// pack two f32 -> packed bf16x2 (round-half-up), 3 VALU inst
__device__ __forceinline__ uint32_t pack_bf16(float a, float b) {
    union { float f; uint32_t u; } x, y; x.f = a; y.f = b;
    return __builtin_amdgcn_perm(y.u + 0x8000u, x.u + 0x8000u, 0x07060302u);
}

__device__ __forceinline__ void g2l16(const unsigned short* g, unsigned short* l) {
    __builtin_amdgcn_global_load_lds(
        (const __attribute__((address_space(1))) void*)g,
        (__attribute__((address_space(3))) void*)l, 16, 0, 0);
}

// -------- fused prep: cast x (fp32->bf16) + cast/transpose weights ----------
__global__ __launch_bounds__(256) void prep_kernel(const float* __restrict__ x,
                                                   const float* __restrict__ w0,
                                                   const float* __restrict__ w1,
                                                   const float* __restrict__ w2,
                                                   const float* __restrict__ w3,
                                                   unsigned short* __restrict__ xb,
                                                   unsigned short* __restrict__ wt) {
    __shared__ float tile[32][33];
    int bid = blockIdx.x;
    int t = threadIdx.x;
    if (bid < 4096) {
        int i = bid * 256 + t;
        const float4* p = (const float4*)x + (size_t)i * 2;
        float4 a = p[0], b = p[1];
        union { unsigned short u[8]; uint4 v; } o;
        o.u[0]=f2bf(a.x); o.u[1]=f2bf(a.y); o.u[2]=f2bf(a.z); o.u[3]=f2bf(a.w);
        o.u[4]=f2bf(b.x); o.u[5]=f2bf(b.y); o.u[6]=f2bf(b.z); o.u[7]=f2bf(b.w);
        ((uint4*)xb)[i] = o.v;
    } else {
        int r = bid - 4096;
        int mat = r >> 10;
        int rem = r & 1023;
        const float* w = (mat == 0) ? w0 : (mat == 1) ? w1 : (mat == 2) ? w2 : w3;
        int n0 = (rem & 31) * 32, k0 = (rem >> 5) * 32;
        int tx = t & 31, ty = t >> 5;   // 32 x 8
        for (int i = 0; i < 32; i += 8)
            tile[ty + i][tx] = w[(size_t)(k0 + ty + i) * D_MODEL + n0 + tx];
        __syncthreads();
        unsigned short* o = wt + (size_t)mat * D_MODEL * D_MODEL;
        for (int i = 0; i < 32; i += 8)
            o[(size_t)(n0 + ty + i) * D_MODEL + (k0 + tx)] = f2bf(tile[tx][ty + i]);
    }
}

// ------------- V transpose: Vb[bh][s][d] -> Vtb[bh][d][s] (bf16) -------------
__global__ __launch_bounds__(256) void transpose_v_kernel(const unsigned short* __restrict__ Vb,
                                                          unsigned short* __restrict__ Vtb) {
    __shared__ unsigned short tile[64][72];
    int st = blockIdx.x;   // s-tile of 64
    int bh = blockIdx.y;
    int t = threadIdx.x;
    int sl = t >> 2, dc = (t & 3) * 16;
    const unsigned short* src = Vb + ((size_t)bh * S_LEN + st * 64 + sl) * HDIM + dc;
    *(uint4*)&tile[sl][dc]     = *(const uint4*)(src);
    *(uint4*)&tile[sl][dc + 8] = *(const uint4*)(src + 8);
    __syncthreads();
    int d = t >> 2, sc = (t & 3) * 16;
    union { unsigned short u[16]; uint4 v[2]; } o;
#pragma unroll
    for (int i = 0; i < 16; i++) o.u[i] = tile[sc + i][d];
    unsigned short* dst = Vtb + ((size_t)bh * HDIM + d) * S_LEN + st * 64 + sc;
    *(uint4*)(dst)     = o.v[0];
    *(uint4*)(dst + 8) = o.v[1];
}

#define MFMA_BF16 __builtin_amdgcn_mfma_f32_16x16x32_bf16

// ========== GEMM: C[M][N] = A[M][K=1024] * Bt[N][K]^T, 256 x (NF*32) tile ===
// (R19 structure, unchanged — R7 pass: QKV <67us, out-proj 2/CU packing.)
#define AS_SLOT 8192    // 256 rows * 32 elems
#define NKT  (D_MODEL / 32)   // 32 k-tiles

template<int NF, int MODE>   // NF = B-frags per wave (BN = NF*32); MODE 0=QKV 1=out
__global__ __launch_bounds__(512, 4) void gemm_kernel(
    const unsigned short* __restrict__ A,
    const unsigned short* __restrict__ Bt,
    unsigned short* __restrict__ Qb,
    unsigned short* __restrict__ Kb,
    unsigned short* __restrict__ Vb,
    float* __restrict__ Out,
    const float* __restrict__ bias) {
    constexpr int BN = NF * 32;          // block N
    constexpr int BS_SLOT = BN * 32;     // B slot elems
    constexpr int NBCH = BN * 4;         // B chunks per tile
    constexpr int NWB = NBCH / 64;       // B-staging wave slices
    __shared__ unsigned short As[3 * AS_SLOT];
    __shared__ unsigned short Bs[3 * BS_SLOT];
    int t = threadIdx.x;

    // T1: XCD-aware remap (bijective: nwg = 768 or 512, both % 8 == 0)
    int gx   = (int)gridDim.x;
    int nwg  = gx * (int)gridDim.y;
    int flat = (int)(blockIdx.y * gridDim.x + blockIdx.x);
    int cpx  = nwg >> 3;
    int wid  = (flat & 7) * cpx + (flat >> 3);
    int m0 = (wid / gx) * 256;
    int n0 = (wid % gx) * BN;

    int wave = t >> 6, lane = t & 63;
    int quad = lane >> 4, lrow = lane & 15;
    int wr = (wave & 3) * 64;            // M offset of wave tile (4 waves)
    int wc = (wave >> 2) * (NF * 16);    // N offset of wave tile (2 waves)

    ffrag acc[4][NF];
    const ffrag fz = {0.f, 0.f, 0.f, 0.f};
#pragma unroll
    for (int i = 0; i < 4; i++)
#pragma unroll
        for (int j = 0; j < NF; j++) acc[i][j] = fz;

    int r0 = t >> 2,        g0 = (t & 3) ^ ((r0 >> 1) & 3);
    int c1 = 512 + t;
    int r1 = c1 >> 2,       g1 = (c1 & 3) ^ ((r1 >> 1) & 3);
    int cbi = t & (NBCH - 1);
    int rB = cbi >> 2,      gB = (cbi & 3) ^ ((rB >> 1) & 3);
    const unsigned short* pA0 = A  + (size_t)(m0 + r0) * D_MODEL + g0 * 8;
    const unsigned short* pA1 = A  + (size_t)(m0 + r1) * D_MODEL + g1 * 8;
    const unsigned short* pB0 = Bt + (size_t)(n0 + rB) * D_MODEL + gB * 8;
    unsigned short* lA0 = &As[(wave * 64) * 8];
    unsigned short* lA1 = &As[(512 + wave * 64) * 8];
    unsigned short* lB0 = &Bs[((wave & (NWB - 1)) * 64) * 8];

    g2l16(pA0, lA0);
    g2l16(pA1, lA1);
    g2l16(pB0, lB0);
    g2l16(pA0 + 32, lA0 + AS_SLOT);
    g2l16(pA1 + 32, lA1 + AS_SLOT);
    g2l16(pB0 + 32, lB0 + BS_SLOT);

    int aCur = 0, aNxt = AS_SLOT, aSpr = 2 * AS_SLOT;
    int bCur = 0, bNxt = BS_SLOT, bSpr = 2 * BS_SLOT;

    for (int kt = 0; kt < NKT - 1; ++kt) {
        asm volatile("s_waitcnt vmcnt(3)\n\ts_barrier" ::: "memory");
        __builtin_amdgcn_sched_barrier(0);
        if (kt + 2 < NKT) {
            int ko = (kt + 2) * 32;
            g2l16(pA0 + ko, lA0 + aSpr);
            g2l16(pA1 + ko, lA1 + aSpr);
            g2l16(pB0 + ko, lB0 + bSpr);
        }
        bfrag af[4], bf[NF];
#pragma unroll
        for (int ni = 0; ni < NF; ni++) {
            int row = wc + ni * 16 + lrow;
            bf[ni] = ld_frag(&Bs[bCur + row * 32 + ((quad ^ ((row >> 1) & 3)) * 8)]);
        }
#pragma unroll
        for (int mi = 0; mi < 4; mi++) {
            int row = wr + mi * 16 + lrow;
            af[mi] = ld_frag(&As[aCur + row * 32 + ((quad ^ ((row >> 1) & 3)) * 8)]);
        }
        __builtin_amdgcn_s_setprio(1);
#pragma unroll
        for (int mi = 0; mi < 4; mi++)
#pragma unroll
            for (int ni = 0; ni < NF; ni++)
                acc[mi][ni] = MFMA_BF16(af[mi], bf[ni], acc[mi][ni], 0, 0, 0);
        __builtin_amdgcn_s_setprio(0);
        int ta = aCur; aCur = aNxt; aNxt = aSpr; aSpr = ta;
        int tb = bCur; bCur = bNxt; bNxt = bSpr; bSpr = tb;
    }
    asm volatile("s_waitcnt vmcnt(0)\n\ts_barrier" ::: "memory");
    __builtin_amdgcn_sched_barrier(0);
    {
        bfrag af[4], bf[NF];
#pragma unroll
        for (int ni = 0; ni < NF; ni++) {
            int row = wc + ni * 16 + lrow;
            bf[ni] = ld_frag(&Bs[bCur + row * 32 + ((quad ^ ((row >> 1) & 3)) * 8)]);
        }
#pragma unroll
        for (int mi = 0; mi < 4; mi++) {
            int row = wr + mi * 16 + lrow;
            af[mi] = ld_frag(&As[aCur + row * 32 + ((quad ^ ((row >> 1) & 3)) * 8)]);
        }
#pragma unroll
        for (int mi = 0; mi < 4; mi++)
#pragma unroll
            for (int ni = 0; ni < NF; ni++)
                acc[mi][ni] = MFMA_BF16(af[mi], bf[ni], acc[mi][ni], 0, 0, 0);
    }

#pragma unroll
    for (int mi = 0; mi < 4; mi++) {
        int row = m0 + wr + mi * 16 + quad * 4;
#pragma unroll
        for (int ni = 0; ni < NF; ni++) {
            int col = n0 + wc + ni * 16 + lrow;
#pragma unroll
            for (int r = 0; r < 4; r++) {
                float v = acc[mi][ni][r];
                int m = row + r;
                if (MODE == 0) {
                    int matid = col >> 10;
                    int nn = col & 1023;
                    int h = nn >> 6, d = nn & 63;
                    int b = m >> 11, s = m & 2047;
                    size_t bh = (size_t)(b * NH + h);
                    if (matid == 0)      Qb[(bh * S_LEN + s) * HDIM + d] = f2bf(v);
                    else if (matid == 1) Kb[(bh * S_LEN + s) * HDIM + d] = f2bf(v);
                    else                 Vb[(bh * S_LEN + s) * HDIM + d] = f2bf(v);
                } else {
                    Out[(size_t)m * D_MODEL + col] = v + bias[col];
                }
            }
        }
    }
}

// ---------------- flash attention v11: R20 = v10 + epilogue conflict fix + setprio ----
// R20a: epilogue O^T store was a 16-way bank conflict (row stride 128B ->
//   every row starts at bank 0; per quarter-wave all 16 lanes hit one bank
//   pair). Counter: 4,128,768 = 1024 blocks x 32 epilogue stores x 126 cyc.
//   Fix: XOR-swizzle 8B slots with x8(lrow) (even -> 16B read pairs stay
//   contiguous); read back at cc ^ (x8(r)>>1). 2 lanes/bank -> free.
// R20b: T5 setprio(1) around QK and PV MFMA clusters (catalog m191: attn
//   +4-7%, measured positive on attn, absent here until now).
#define SCALE2 0.18033688f  // 1/sqrt(64) * log2(e)
#define CSHIFT 4.0f
#define KVBUF 4096          // elems per K (or V) buffer: 64*64

__global__ __launch_bounds__(256, 4) void attn_kernel(
    const unsigned short* __restrict__ Qb,
    const unsigned short* __restrict__ Kb,
    const unsigned short* __restrict__ Vtb,
    unsigned short* __restrict__ ctxb) {
    __shared__ unsigned short Ks[2 * KVBUF];      // [buf][key][d]  swizzled
    __shared__ unsigned short Vs[2 * KVBUF];      // [buf][d][key]  swizzled
    __shared__ unsigned short Ps[4 * 16 * 64];    // per wave: [q(16)][key(64)] swizzled
    int flat = (int)(blockIdx.y * gridDim.x + blockIdx.x);   // 1024 blocks
    int wid  = (flat & 7) * 128 + (flat >> 3);
    int bx = wid & 15;    // 0..15
    int bh = wid >> 4;    // 0..63
    int t = threadIdx.x;
    int wave = t >> 6, lane = t & 63;
    int quad = lane >> 4, lrow = lane & 15;
    int swz = lrow & 7;
    int ca = (quad ^ swz) * 8;        // physical elem offset of logical chunk quad
    int cb = ca ^ 32;                 // logical chunk quad+4

    union { uint4 u; bfrag b; } one_u;
    one_u.u.x = 0x3F803F80u; one_u.u.y = 0x3F803F80u;
    one_u.u.z = 0x3F803F80u; one_u.u.w = 0x3F803F80u;
    bfrag onef = one_u.b;             // all-ones A-frag for l row-sum MFMA

    const unsigned short* Qg = Qb + (size_t)bh * S_LEN * HDIM;
    const unsigned short* Kg = Kb + (size_t)bh * S_LEN * HDIM;
    const unsigned short* Vg = Vtb + (size_t)bh * HDIM * S_LEN;
    int b = bh >> 4, h = bh & 15;

    int c0 = t, c1 = 256 + t;
    int kr0 = c0 >> 3, kp0 = (c0 & 7) ^ (kr0 & 7);
    int kr1 = c1 >> 3, kp1 = (c1 & 7) ^ (kr1 & 7);
    const unsigned short* pK0 = Kg + (size_t)kr0 * HDIM + kp0 * 8;
    const unsigned short* pK1 = Kg + (size_t)kr1 * HDIM + kp1 * 8;
    const unsigned short* pV0 = Vg + (size_t)kr0 * S_LEN + kp0 * 8;
    const unsigned short* pV1 = Vg + (size_t)kr1 * S_LEN + kp1 * 8;
    unsigned short* lK0 = &Ks[(wave * 64) * 8];
    unsigned short* lK1 = &Ks[(256 + wave * 64) * 8];
    unsigned short* lV0 = &Vs[(wave * 64) * 8];
    unsigned short* lV1 = &Vs[(256 + wave * 64) * 8];
    unsigned short* Pw = &Ps[wave * 16 * 64];

    // epilogue swizzle keys (R20a)
    int x8 = (((lrow >> 1) & 3) << 1) | (((lrow >> 3) & 1) << 3);   // even
    int ql = lane >> 3, cc = lane & 7;

    for (int ph = 0; ph < 2; ph++) {
        int qc = ph == 0 ? (31 - bx) : bx;   // 64-row q chunk index
        int qw = qc * 64 + wave * 16;
        int nk = qc + 1;

        bfrag qf[2];
#pragma unroll
        for (int c = 0; c < 2; c++)
            qf[c] = ld_frag(Qg + (size_t)(qw + lrow) * HDIM + c * 32 + quad * 8);

        ffrag acc[4];
        ffrag acc_l;
        const ffrag fz = {0.f, 0.f, 0.f, 0.f};
#pragma unroll
        for (int d = 0; d < 4; d++) acc[d] = fz;
        acc_l = fz;

        __syncthreads();
        g2l16(pK0, lK0);
        g2l16(pK1, lK1);
        g2l16(pV0, lV0);
        g2l16(pV1, lV1);

        for (int kt = 0; kt < nk; kt++) {
            int kbase = kt * 64;
            int buf = (kt & 1) * KVBUF;
            __syncthreads();
            if (kt + 1 < nk) {
                int nb = ((kt + 1) & 1) * KVBUF;
                size_t krow_off = (size_t)(kbase + 64) * HDIM;
                g2l16(pK0 + krow_off, lK0 + nb);
                g2l16(pK1 + krow_off, lK1 + nb);
                g2l16(pV0 + kbase + 64, lV0 + nb);
                g2l16(pV1 + kbase + 64, lV1 + nb);
            }

            // ---- S^T = K Q^T ----
            ffrag sf[4];
            __builtin_amdgcn_s_setprio(1);
#pragma unroll
            for (int ki = 0; ki < 4; ki++) {
                int krow = buf + (ki * 16 + lrow) * 64;
                bfrag ka = ld_frag(&Ks[krow + ca]);
                bfrag kb = ld_frag(&Ks[krow + cb]);
                ffrag s = fz;
                s = __builtin_amdgcn_mfma_f32_16x16x32_bf16(ka, qf[0], s, 0, 0, 0);
                s = __builtin_amdgcn_mfma_f32_16x16x32_bf16(kb, qf[1], s, 0, 0, 0);
                sf[ki] = s;
            }
            __builtin_amdgcn_s_setprio(0);

            // ---- fixed-shift softmax (mask only on the diagonal tile) ----
            int qg = qw + lrow;                  // this lane's q
            bool need_mask = (kt == nk - 1);     // block-uniform
            float sv[16];
#pragma unroll
            for (int ki = 0; ki < 4; ki++)
#pragma unroll
                for (int r = 0; r < 4; r++) {
                    float v = sf[ki][r];
                    if (need_mask) {
                        int key = kbase + ki * 16 + quad * 4 + r;
                        v = (key <= qg) ? v : -3.0e38f;
                    }
                    sv[ki * 4 + r] = fast_exp2(__builtin_fmaf(v, SCALE2, -CSHIFT));
                }
            int prow = lrow * 64;
#pragma unroll
            for (int ki = 0; ki < 4; ki++) {
                uint2 w2;
                w2.x = pack_bf16(sv[ki * 4 + 0], sv[ki * 4 + 1]);
                w2.y = pack_bf16(sv[ki * 4 + 2], sv[ki * 4 + 3]);
                int pc = ((ki * 2 + (quad >> 1)) ^ swz) * 8 + (quad & 1) * 4;
                *(uint2*)&Pw[prow + pc] = w2;
            }

            // ---- O^T += V^T P^T ----  (Pw wave-private, DS in-order: no barrier)
            bfrag pf0 = ld_frag(&Pw[prow + ca]);
            bfrag pf1 = ld_frag(&Pw[prow + cb]);
            acc_l = __builtin_amdgcn_mfma_f32_16x16x32_bf16(onef, pf0, acc_l, 0, 0, 0);
            acc_l = __builtin_amdgcn_mfma_f32_16x16x32_bf16(onef, pf1, acc_l, 0, 0, 0);
            __builtin_amdgcn_s_setprio(1);
#pragma unroll
            for (int di = 0; di < 4; di++) {
                int vrow = buf + (di * 16 + lrow) * 64;
                bfrag va = ld_frag(&Vs[vrow + ca]);
                bfrag vb = ld_frag(&Vs[vrow + cb]);
                acc[di] = __builtin_amdgcn_mfma_f32_16x16x32_bf16(va, pf0, acc[di], 0, 0, 0);
                acc[di] = __builtin_amdgcn_mfma_f32_16x16x32_bf16(vb, pf1, acc[di], 0, 0, 0);
            }
            __builtin_amdgcn_s_setprio(0);
        }

        // epilogue: transpose O^T -> O via wave-private LDS, coalesced 16B stores.
        // R20a: XOR-swizzled 8B slots -> 2 lanes/bank (was 16-way, 126 cyc/store).
        float rl = __builtin_amdgcn_rcpf(acc_l[0]);  // all rows equal; lane lrow=q
#pragma unroll
        for (int di = 0; di < 4; di++) {
            uint2 w2;
            w2.x = pack_bf16(acc[di][0] * rl, acc[di][1] * rl);
            w2.y = pack_bf16(acc[di][2] * rl, acc[di][3] * rl);
            int slot = (4 * di + quad) ^ x8;
            *(uint2*)&Pw[lrow * 64 + slot * 4] = w2;
        }
#pragma unroll
        for (int p = 0; p < 2; p++) {
            int r = p * 8 + ql;
            int rx = ((r >> 1) & 3) | ((r & 8) >> 1);   // = x8(r) >> 1
            uint4 vv = *(uint4*)&Pw[r * 64 + (cc ^ rx) * 8];
            int q = qw + p * 8 + ql;
            *(uint4*)(ctxb + ((size_t)b * S_LEN + q) * D_MODEL + h * HDIM + cc * 8) = vv;
        }
    }
}

extern "C" void kernel_launch(void* const* d_in, const int* in_sizes, int n_in,
                              void* d_out, int out_size, void* d_ws, size_t ws_size,
                              hipStream_t stream) {
    const float* x   = (const float*)d_in[0];
    const float* W_q = (const float*)d_in[1];
    const float* W_k = (const float*)d_in[2];
    const float* W_v = (const float*)d_in[3];
    const float* W_o = (const float*)d_in[4];
    const float* b_o = (const float*)d_in[5];
    float* out = (float*)d_out;

    // workspace carve (elems, ushort).  Vb (row-layout V) aliases ctxb:
    // Vb is dead after transpose_v, before attn writes ctxb.
    unsigned short* xb   = (unsigned short*)d_ws;                    // 8192*1024
    unsigned short* Wt   = xb + (size_t)8192 * 1024;                 // 4*1024*1024
    unsigned short* Qb   = Wt + (size_t)4 * 1024 * 1024;             // 64*2048*64
    unsigned short* Kb   = Qb + (size_t)64 * 2048 * 64;
    unsigned short* Vtb  = Kb + (size_t)64 * 2048 * 64;
    unsigned short* ctxb = Vtb + (size_t)64 * 2048 * 64;             // 8192*1024
    unsigned short* Vb   = ctxb;
    unsigned short* Wto  = Wt + (size_t)3 * 1024 * 1024;

    // fused cast + weight transpose (one launch)
    prep_kernel<<<8192, 256, 0, stream>>>(x, W_q, W_k, W_v, W_o, xb, Wt);
    // QKV: M=8192, N=3072; 256x128 tiles (NF=4) -> 24x32 = 768 blocks (2/CU)
    gemm_kernel<4, 0><<<dim3(24, 32), 512, 0, stream>>>(xb, Wt, Qb, Kb, Vb, nullptr, nullptr);
    // V transpose [s][d] -> [d][s]
    transpose_v_kernel<<<dim3(32, 64), 256, 0, stream>>>(Vb, Vtb);
    // attention (split-q: block bx does 64-row chunks 31-bx then bx; 33 tiles each)
    attn_kernel<<<dim3(16, 64), 256, 0, stream>>>(Qb, Kb, Vtb, ctxb);
    // out proj: M=8192, N=1024, + bias; 256x64 tiles (NF=2) -> 16x32 = 512
    // blocks = EXACTLY 2/CU on all 256 CUs
    gemm_kernel<2, 1><<<dim3(16, 32), 512, 0, stream>>>(ctxb, Wto, nullptr, nullptr, nullptr, out, b_o);
}

// Round 10
// 244.152 us; speedup vs baseline: 1.0130x; 1.0130x over previous
//
#include <hip/hip_runtime.h>
#include <cstdint>

#define S_LEN 2048
#define D_MODEL 1024
#define NH 16
#define HDIM 64
#define BATCH 4

typedef __attribute__((ext_vector_type(8))) __bf16 bfrag;   // 8 bf16 = 4 VGPR
typedef __attribute__((ext_vector_type(4))) float ffrag;    // 4 f32 acc

__device__ __forceinline__ unsigned short f2bf(float f) {
    union { float f; uint32_t u; } v; v.f = f;
    uint32_t u = v.u;
    u += 0x7fff + ((u >> 16) & 1);   // round-to-nearest-even
    return (unsigned short)(u >> 16);
}

__device__ __forceinline__ bfrag ld_frag(const unsigned short* p) {
    union { uint4 u; bfrag b; } x;
    x.u = *(const uint4*)p;
    return x.b;
}

__device__ __forceinline__ float fast_exp2(float x) {
#if __has_builtin(__builtin_amdgcn_exp2f)
    return __builtin_amdgcn_exp2f(x);
#else
    return __expf(x * 0.6931471805599453f);
#endif
}

// pack two f32 -> packed bf16x2 (round-half-up), 3 VALU inst
__device__ __forceinline__ uint32_t pack_bf16(float a, float b) {
    union { float f; uint32_t u; } x, y; x.f = a; y.f = b;
    return __builtin_amdgcn_perm(y.u + 0x8000u, x.u + 0x8000u, 0x07060302u);
}

__device__ __forceinline__ void g2l16(const unsigned short* g, unsigned short* l) {
    __builtin_amdgcn_global_load_lds(
        (const __attribute__((address_space(1))) void*)g,
        (__attribute__((address_space(3))) void*)l, 16, 0, 0);
}

// -------- fused prep: cast x (fp32->bf16) + cast/transpose weights ----------
__global__ __launch_bounds__(256) void prep_kernel(const float* __restrict__ x,
                                                   const float* __restrict__ w0,
                                                   const float* __restrict__ w1,
                                                   const float* __restrict__ w2,
                                                   const float* __restrict__ w3,
                                                   unsigned short* __restrict__ xb,
                                                   unsigned short* __restrict__ wt) {
    __shared__ float tile[32][33];
    int bid = blockIdx.x;
    int t = threadIdx.x;
    if (bid < 4096) {
        int i = bid * 256 + t;
        const float4* p = (const float4*)x + (size_t)i * 2;
        float4 a = p[0], b = p[1];
        union { unsigned short u[8]; uint4 v; } o;
        o.u[0]=f2bf(a.x); o.u[1]=f2bf(a.y); o.u[2]=f2bf(a.z); o.u[3]=f2bf(a.w);
        o.u[4]=f2bf(b.x); o.u[5]=f2bf(b.y); o.u[6]=f2bf(b.z); o.u[7]=f2bf(b.w);
        ((uint4*)xb)[i] = o.v;
    } else {
        int r = bid - 4096;
        int mat = r >> 10;
        int rem = r & 1023;
        const float* w = (mat == 0) ? w0 : (mat == 1) ? w1 : (mat == 2) ? w2 : w3;
        int n0 = (rem & 31) * 32, k0 = (rem >> 5) * 32;
        int tx = t & 31, ty = t >> 5;   // 32 x 8
        for (int i = 0; i < 32; i += 8)
            tile[ty + i][tx] = w[(size_t)(k0 + ty + i) * D_MODEL + n0 + tx];
        __syncthreads();
        unsigned short* o = wt + (size_t)mat * D_MODEL * D_MODEL;
        for (int i = 0; i < 32; i += 8)
            o[(size_t)(n0 + ty + i) * D_MODEL + (k0 + tx)] = f2bf(tile[tx][ty + i]);
    }
}

#define MFMA_BF16 __builtin_amdgcn_mfma_f32_16x16x32_bf16

// ========== GEMM: C[M][N] = A[M][K=1024] * Bt[N][K]^T, 256 x (NF*32) tile ===
// R19 structure (R7/R8 pass). R21/R22: V TRANSPOSE FUSED INTO EPILOGUE —
// transpose_v kernel deleted (was ~8us + 32MB HBM round-trip). V blocks
// (matid==2, block-uniform since BN=128) bounce their wave-private 64x64
// (s x d) acc tile through a 64x72 LDS tile (one barrier; then wave-private
// DS in-order, same guarantee as attn's Pw) and write Vtb[d][s] with the
// transpose_v-proven 4-lane/128B coalesced pattern.
// R22 FIX: R9 failed (absmax 5.5) because h0 omitted the `& 1023` matrix-
// offset strip (n0 >= 2048 for V -> h0 in [32,48) -> bh overflow; Vtb never
// written, writes clobbered past it). Q/K path always had the mask.
#define AS_SLOT 8192    // 256 rows * 32 elems
#define NKT  (D_MODEL / 32)   // 32 k-tiles

template<int NF, int MODE>   // NF = B-frags per wave (BN = NF*32); MODE 0=QKV 1=out
__global__ __launch_bounds__(512, 4) void gemm_kernel(
    const unsigned short* __restrict__ A,
    const unsigned short* __restrict__ Bt,
    unsigned short* __restrict__ Qb,
    unsigned short* __restrict__ Kb,
    unsigned short* __restrict__ Vtb,
    float* __restrict__ Out,
    const float* __restrict__ bias) {
    constexpr int BN = NF * 32;          // block N
    constexpr int BS_SLOT = BN * 32;     // B slot elems
    constexpr int NBCH = BN * 4;         // B chunks per tile
    constexpr int NWB = NBCH / 64;       // B-staging wave slices
    __shared__ unsigned short Smem[3 * AS_SLOT + 3 * BS_SLOT];
    unsigned short* As = Smem;
    unsigned short* Bs = Smem + 3 * AS_SLOT;
    int t = threadIdx.x;

    // T1: XCD-aware remap (bijective: nwg = 768 or 512, both % 8 == 0)
    int gx   = (int)gridDim.x;
    int nwg  = gx * (int)gridDim.y;
    int flat = (int)(blockIdx.y * gridDim.x + blockIdx.x);
    int cpx  = nwg >> 3;
    int wid  = (flat & 7) * cpx + (flat >> 3);
    int m0 = (wid / gx) * 256;
    int n0 = (wid % gx) * BN;

    int wave = t >> 6, lane = t & 63;
    int quad = lane >> 4, lrow = lane & 15;
    int wr = (wave & 3) * 64;            // M offset of wave tile (4 waves)
    int wc = (wave >> 2) * (NF * 16);    // N offset of wave tile (2 waves)

    ffrag acc[4][NF];
    const ffrag fz = {0.f, 0.f, 0.f, 0.f};
#pragma unroll
    for (int i = 0; i < 4; i++)
#pragma unroll
        for (int j = 0; j < NF; j++) acc[i][j] = fz;

    int r0 = t >> 2,        g0 = (t & 3) ^ ((r0 >> 1) & 3);
    int c1 = 512 + t;
    int r1 = c1 >> 2,       g1 = (c1 & 3) ^ ((r1 >> 1) & 3);
    int cbi = t & (NBCH - 1);
    int rB = cbi >> 2,      gB = (cbi & 3) ^ ((rB >> 1) & 3);
    const unsigned short* pA0 = A  + (size_t)(m0 + r0) * D_MODEL + g0 * 8;
    const unsigned short* pA1 = A  + (size_t)(m0 + r1) * D_MODEL + g1 * 8;
    const unsigned short* pB0 = Bt + (size_t)(n0 + rB) * D_MODEL + gB * 8;
    unsigned short* lA0 = &As[(wave * 64) * 8];
    unsigned short* lA1 = &As[(512 + wave * 64) * 8];
    unsigned short* lB0 = &Bs[((wave & (NWB - 1)) * 64) * 8];

    g2l16(pA0, lA0);
    g2l16(pA1, lA1);
    g2l16(pB0, lB0);
    g2l16(pA0 + 32, lA0 + AS_SLOT);
    g2l16(pA1 + 32, lA1 + AS_SLOT);
    g2l16(pB0 + 32, lB0 + BS_SLOT);

    int aCur = 0, aNxt = AS_SLOT, aSpr = 2 * AS_SLOT;
    int bCur = 0, bNxt = BS_SLOT, bSpr = 2 * BS_SLOT;

    for (int kt = 0; kt < NKT - 1; ++kt) {
        asm volatile("s_waitcnt vmcnt(3)\n\ts_barrier" ::: "memory");
        __builtin_amdgcn_sched_barrier(0);
        if (kt + 2 < NKT) {
            int ko = (kt + 2) * 32;
            g2l16(pA0 + ko, lA0 + aSpr);
            g2l16(pA1 + ko, lA1 + aSpr);
            g2l16(pB0 + ko, lB0 + bSpr);
        }
        bfrag af[4], bf[NF];
#pragma unroll
        for (int ni = 0; ni < NF; ni++) {
            int row = wc + ni * 16 + lrow;
            bf[ni] = ld_frag(&Bs[bCur + row * 32 + ((quad ^ ((row >> 1) & 3)) * 8)]);
        }
#pragma unroll
        for (int mi = 0; mi < 4; mi++) {
            int row = wr + mi * 16 + lrow;
            af[mi] = ld_frag(&As[aCur + row * 32 + ((quad ^ ((row >> 1) & 3)) * 8)]);
        }
        __builtin_amdgcn_s_setprio(1);
#pragma unroll
        for (int mi = 0; mi < 4; mi++)
#pragma unroll
            for (int ni = 0; ni < NF; ni++)
                acc[mi][ni] = MFMA_BF16(af[mi], bf[ni], acc[mi][ni], 0, 0, 0);
        __builtin_amdgcn_s_setprio(0);
        int ta = aCur; aCur = aNxt; aNxt = aSpr; aSpr = ta;
        int tb = bCur; bCur = bNxt; bNxt = bSpr; bSpr = tb;
    }
    asm volatile("s_waitcnt vmcnt(0)\n\ts_barrier" ::: "memory");
    __builtin_amdgcn_sched_barrier(0);
    {
        bfrag af[4], bf[NF];
#pragma unroll
        for (int ni = 0; ni < NF; ni++) {
            int row = wc + ni * 16 + lrow;
            bf[ni] = ld_frag(&Bs[bCur + row * 32 + ((quad ^ ((row >> 1) & 3)) * 8)]);
        }
#pragma unroll
        for (int mi = 0; mi < 4; mi++) {
            int row = wr + mi * 16 + lrow;
            af[mi] = ld_frag(&As[aCur + row * 32 + ((quad ^ ((row >> 1) & 3)) * 8)]);
        }
#pragma unroll
        for (int mi = 0; mi < 4; mi++)
#pragma unroll
            for (int ni = 0; ni < NF; ni++)
                acc[mi][ni] = MFMA_BF16(af[mi], bf[ni], acc[mi][ni], 0, 0, 0);
    }

    if constexpr (MODE == 0) {
        int matid = n0 >> 10;          // block-uniform (BN=128 divides 1024)
        if (matid == 2) {
            // ---- R21: fused V transpose via LDS bounce ----
            __syncthreads();           // all waves done reading As/Bs ring
            unsigned short* Lw = &Smem[wave * (64 * 72)];   // wave-private 64x72
#pragma unroll
            for (int mi = 0; mi < 4; mi++)
#pragma unroll
                for (int ni = 0; ni < NF; ni++)
#pragma unroll
                    for (int r = 0; r < 4; r++)
                        Lw[(mi * 16 + quad * 4 + r) * 72 + ni * 16 + lrow] =
                            f2bf(acc[mi][ni][r]);
            // wave-private DS in-order: no barrier needed before readback
            int h0 = ((n0 + wc) & 1023) >> 6;      // head (R22 FIX: strip matrix offset)
            int bb = m0 >> 11;                     // batch (block-uniform)
            size_t bh = (size_t)bb * NH + h0;
            int sbase = (m0 + wr) & 2047;          // s of s_local=0
            unsigned short* Vt = Vtb + bh * (size_t)HDIM * S_LEN;
#pragma unroll
            for (int p = 0; p < 4; p++) {
                int d  = (lane >> 2) + p * 16;
                int sc = (lane & 3) * 16;
                union { unsigned short u[16]; uint4 v[2]; } o;
#pragma unroll
                for (int i = 0; i < 16; i++) o.u[i] = Lw[(sc + i) * 72 + d];
                unsigned short* dst = Vt + (size_t)d * S_LEN + sbase + sc;
                *(uint4*)(dst)     = o.v[0];
                *(uint4*)(dst + 8) = o.v[1];
            }
        } else {
            // Q/K scatter (unchanged, fully unrolled — rule #20)
#pragma unroll
            for (int mi = 0; mi < 4; mi++) {
                int row = m0 + wr + mi * 16 + quad * 4;
#pragma unroll
                for (int ni = 0; ni < NF; ni++) {
                    int col = n0 + wc + ni * 16 + lrow;
#pragma unroll
                    for (int r = 0; r < 4; r++) {
                        float v = acc[mi][ni][r];
                        int m = row + r;
                        int nn = col & 1023;
                        int h = nn >> 6, d = nn & 63;
                        int b = m >> 11, s = m & 2047;
                        size_t bh = (size_t)(b * NH + h);
                        if (matid == 0) Qb[(bh * S_LEN + s) * HDIM + d] = f2bf(v);
                        else            Kb[(bh * S_LEN + s) * HDIM + d] = f2bf(v);
                    }
                }
            }
        }
    } else {
#pragma unroll
        for (int mi = 0; mi < 4; mi++) {
            int row = m0 + wr + mi * 16 + quad * 4;
#pragma unroll
            for (int ni = 0; ni < NF; ni++) {
                int col = n0 + wc + ni * 16 + lrow;
#pragma unroll
                for (int r = 0; r < 4; r++) {
                    int m = row + r;
                    Out[(size_t)m * D_MODEL + col] = acc[mi][ni][r] + bias[col];
                }
            }
        }
    }
}

// ---------------- flash attention v11 (unchanged from R8 pass) ----------------
#define SCALE2 0.18033688f  // 1/sqrt(64) * log2(e)
#define CSHIFT 4.0f
#define KVBUF 4096          // elems per K (or V) buffer: 64*64

__global__ __launch_bounds__(256, 4) void attn_kernel(
    const unsigned short* __restrict__ Qb,
    const unsigned short* __restrict__ Kb,
    const unsigned short* __restrict__ Vtb,
    unsigned short* __restrict__ ctxb) {
    __shared__ unsigned short Ks[2 * KVBUF];      // [buf][key][d]  swizzled
    __shared__ unsigned short Vs[2 * KVBUF];      // [buf][d][key]  swizzled
    __shared__ unsigned short Ps[4 * 16 * 64];    // per wave: [q(16)][key(64)] swizzled
    int flat = (int)(blockIdx.y * gridDim.x + blockIdx.x);   // 1024 blocks
    int wid  = (flat & 7) * 128 + (flat >> 3);
    int bx = wid & 15;    // 0..15
    int bh = wid >> 4;    // 0..63
    int t = threadIdx.x;
    int wave = t >> 6, lane = t & 63;
    int quad = lane >> 4, lrow = lane & 15;
    int swz = lrow & 7;
    int ca = (quad ^ swz) * 8;        // physical elem offset of logical chunk quad
    int cb = ca ^ 32;                 // logical chunk quad+4

    union { uint4 u; bfrag b; } one_u;
    one_u.u.x = 0x3F803F80u; one_u.u.y = 0x3F803F80u;
    one_u.u.z = 0x3F803F80u; one_u.u.w = 0x3F803F80u;
    bfrag onef = one_u.b;             // all-ones A-frag for l row-sum MFMA

    const unsigned short* Qg = Qb + (size_t)bh * S_LEN * HDIM;
    const unsigned short* Kg = Kb + (size_t)bh * S_LEN * HDIM;
    const unsigned short* Vg = Vtb + (size_t)bh * HDIM * S_LEN;
    int b = bh >> 4, h = bh & 15;

    int c0 = t, c1 = 256 + t;
    int kr0 = c0 >> 3, kp0 = (c0 & 7) ^ (kr0 & 7);
    int kr1 = c1 >> 3, kp1 = (c1 & 7) ^ (kr1 & 7);
    const unsigned short* pK0 = Kg + (size_t)kr0 * HDIM + kp0 * 8;
    const unsigned short* pK1 = Kg + (size_t)kr1 * HDIM + kp1 * 8;
    const unsigned short* pV0 = Vg + (size_t)kr0 * S_LEN + kp0 * 8;
    const unsigned short* pV1 = Vg + (size_t)kr1 * S_LEN + kp1 * 8;
    unsigned short* lK0 = &Ks[(wave * 64) * 8];
    unsigned short* lK1 = &Ks[(256 + wave * 64) * 8];
    unsigned short* lV0 = &Vs[(wave * 64) * 8];
    unsigned short* lV1 = &Vs[(256 + wave * 64) * 8];
    unsigned short* Pw = &Ps[wave * 16 * 64];

    // epilogue swizzle keys (R20a)
    int x8 = (((lrow >> 1) & 3) << 1) | (((lrow >> 3) & 1) << 3);   // even
    int ql = lane >> 3, cc = lane & 7;

    for (int ph = 0; ph < 2; ph++) {
        int qc = ph == 0 ? (31 - bx) : bx;   // 64-row q chunk index
        int qw = qc * 64 + wave * 16;
        int nk = qc + 1;

        bfrag qf[2];
#pragma unroll
        for (int c = 0; c < 2; c++)
            qf[c] = ld_frag(Qg + (size_t)(qw + lrow) * HDIM + c * 32 + quad * 8);

        ffrag acc[4];
        ffrag acc_l;
        const ffrag fz = {0.f, 0.f, 0.f, 0.f};
#pragma unroll
        for (int d = 0; d < 4; d++) acc[d] = fz;
        acc_l = fz;

        __syncthreads();
        g2l16(pK0, lK0);
        g2l16(pK1, lK1);
        g2l16(pV0, lV0);
        g2l16(pV1, lV1);

        for (int kt = 0; kt < nk; kt++) {
            int kbase = kt * 64;
            int buf = (kt & 1) * KVBUF;
            __syncthreads();
            if (kt + 1 < nk) {
                int nb = ((kt + 1) & 1) * KVBUF;
                size_t krow_off = (size_t)(kbase + 64) * HDIM;
                g2l16(pK0 + krow_off, lK0 + nb);
                g2l16(pK1 + krow_off, lK1 + nb);
                g2l16(pV0 + kbase + 64, lV0 + nb);
                g2l16(pV1 + kbase + 64, lV1 + nb);
            }

            // ---- S^T = K Q^T ----
            ffrag sf[4];
            __builtin_amdgcn_s_setprio(1);
#pragma unroll
            for (int ki = 0; ki < 4; ki++) {
                int krow = buf + (ki * 16 + lrow) * 64;
                bfrag ka = ld_frag(&Ks[krow + ca]);
                bfrag kb = ld_frag(&Ks[krow + cb]);
                ffrag s = fz;
                s = __builtin_amdgcn_mfma_f32_16x16x32_bf16(ka, qf[0], s, 0, 0, 0);
                s = __builtin_amdgcn_mfma_f32_16x16x32_bf16(kb, qf[1], s, 0, 0, 0);
                sf[ki] = s;
            }
            __builtin_amdgcn_s_setprio(0);

            // ---- fixed-shift softmax (mask only on the diagonal tile) ----
            int qg = qw + lrow;                  // this lane's q
            bool need_mask = (kt == nk - 1);     // block-uniform
            float sv[16];
#pragma unroll
            for (int ki = 0; ki < 4; ki++)
#pragma unroll
                for (int r = 0; r < 4; r++) {
                    float v = sf[ki][r];
                    if (need_mask) {
                        int key = kbase + ki * 16 + quad * 4 + r;
                        v = (key <= qg) ? v : -3.0e38f;
                    }
                    sv[ki * 4 + r] = fast_exp2(__builtin_fmaf(v, SCALE2, -CSHIFT));
                }
            int prow = lrow * 64;
#pragma unroll
            for (int ki = 0; ki < 4; ki++) {
                uint2 w2;
                w2.x = pack_bf16(sv[ki * 4 + 0], sv[ki * 4 + 1]);
                w2.y = pack_bf16(sv[ki * 4 + 2], sv[ki * 4 + 3]);
                int pc = ((ki * 2 + (quad >> 1)) ^ swz) * 8 + (quad & 1) * 4;
                *(uint2*)&Pw[prow + pc] = w2;
            }

            // ---- O^T += V^T P^T ----  (Pw wave-private, DS in-order: no barrier)
            bfrag pf0 = ld_frag(&Pw[prow + ca]);
            bfrag pf1 = ld_frag(&Pw[prow + cb]);
            acc_l = __builtin_amdgcn_mfma_f32_16x16x32_bf16(onef, pf0, acc_l, 0, 0, 0);
            acc_l = __builtin_amdgcn_mfma_f32_16x16x32_bf16(onef, pf1, acc_l, 0, 0, 0);
            __builtin_amdgcn_s_setprio(1);
#pragma unroll
            for (int di = 0; di < 4; di++) {
                int vrow = buf + (di * 16 + lrow) * 64;
                bfrag va = ld_frag(&Vs[vrow + ca]);
                bfrag vb = ld_frag(&Vs[vrow + cb]);
                acc[di] = __builtin_amdgcn_mfma_f32_16x16x32_bf16(va, pf0, acc[di], 0, 0, 0);
                acc[di] = __builtin_amdgcn_mfma_f32_16x16x32_bf16(vb, pf1, acc[di], 0, 0, 0);
            }
            __builtin_amdgcn_s_setprio(0);
        }

        // epilogue: transpose O^T -> O via wave-private LDS, coalesced 16B stores.
        // R20a: XOR-swizzled 8B slots -> 2 lanes/bank (was 16-way, 126 cyc/store).
        float rl = __builtin_amdgcn_rcpf(acc_l[0]);  // all rows equal; lane lrow=q
#pragma unroll
        for (int di = 0; di < 4; di++) {
            uint2 w2;
            w2.x = pack_bf16(acc[di][0] * rl, acc[di][1] * rl);
            w2.y = pack_bf16(acc[di][2] * rl, acc[di][3] * rl);
            int slot = (4 * di + quad) ^ x8;
            *(uint2*)&Pw[lrow * 64 + slot * 4] = w2;
        }
#pragma unroll
        for (int p = 0; p < 2; p++) {
            int r = p * 8 + ql;
            int rx = ((r >> 1) & 3) | ((r & 8) >> 1);   // = x8(r) >> 1
            uint4 vv = *(uint4*)&Pw[r * 64 + (cc ^ rx) * 8];
            int q = qw + p * 8 + ql;
            *(uint4*)(ctxb + ((size_t)b * S_LEN + q) * D_MODEL + h * HDIM + cc * 8) = vv;
        }
    }
}

extern "C" void kernel_launch(void* const* d_in, const int* in_sizes, int n_in,
                              void* d_out, int out_size, void* d_ws, size_t ws_size,
                              hipStream_t stream) {
    const float* x   = (const float*)d_in[0];
    const float* W_q = (const float*)d_in[1];
    const float* W_k = (const float*)d_in[2];
    const float* W_v = (const float*)d_in[3];
    const float* W_o = (const float*)d_in[4];
    const float* b_o = (const float*)d_in[5];
    float* out = (float*)d_out;

    // workspace carve (elems, ushort). R21: Vb gone — gemm writes Vtb direct.
    unsigned short* xb   = (unsigned short*)d_ws;                    // 8192*1024
    unsigned short* Wt   = xb + (size_t)8192 * 1024;                 // 4*1024*1024
    unsigned short* Qb   = Wt + (size_t)4 * 1024 * 1024;             // 64*2048*64
    unsigned short* Kb   = Qb + (size_t)64 * 2048 * 64;
    unsigned short* Vtb  = Kb + (size_t)64 * 2048 * 64;
    unsigned short* ctxb = Vtb + (size_t)64 * 2048 * 64;             // 8192*1024
    unsigned short* Wto  = Wt + (size_t)3 * 1024 * 1024;

    // fused cast + weight transpose (one launch)
    prep_kernel<<<8192, 256, 0, stream>>>(x, W_q, W_k, W_v, W_o, xb, Wt);
    // QKV: M=8192, N=3072; 256x128 tiles (NF=4) -> 24x32 = 768 blocks (2/CU);
    // V blocks write Vtb[d][s] directly (fused transpose)
    gemm_kernel<4, 0><<<dim3(24, 32), 512, 0, stream>>>(xb, Wt, Qb, Kb, Vtb, nullptr, nullptr);
    // attention (split-q: block bx does 64-row chunks 31-bx then bx; 33 tiles each)
    attn_kernel<<<dim3(16, 64), 256, 0, stream>>>(Qb, Kb, Vtb, ctxb);
    // out proj: M=8192, N=1024, + bias; 256x64 tiles (NF=2) -> 16x32 = 512
    // blocks = EXACTLY 2/CU on all 256 CUs
    gemm_kernel<2, 1><<<dim3(16, 32), 512, 0, stream>>>(ctxb, Wto, nullptr, nullptr, nullptr, out, b_o);
}